// Round 2
// baseline (9519.463 us; speedup 1.0000x reference)
//
#include <hip/hip_runtime.h>
#include <hip/hip_bf16.h>

typedef __hip_bfloat16 bf16;

__device__ __forceinline__ float b2f(bf16 v) { return __bfloat162float(v); }
__device__ __forceinline__ bf16 f2b(float v) { return __float2bfloat16(v); }

constexpr int B = 4, C = 64, H = 256, W = 256, Hh = 128, Wh = 128, C8 = 512;
constexpr int HWh = Hh * Wh;   // 16384
constexpr int HWf = H * W;     // 65536

// ---------------------------------------------------------------- bwt
// x (B,64,256,256) fp32 -> A (B,512,128,128) bf16, 8 bands of +/- combos of the 4 phases
__global__ __launch_bounds__(256) void bwt_kernel(const float* __restrict__ x,
                                                  bf16* __restrict__ A) {
    int idx = blockIdx.x * 256 + threadIdx.x;   // B*64*128*128 threads
    int j = idx & (Wh - 1);
    int i = (idx >> 7) & (Hh - 1);
    int c = (idx >> 14) & 63;
    int b = idx >> 20;
    const float* xp = x + (((size_t)(b * C + c) * H + 2 * i) * W + 2 * j);
    float x1 = xp[0]     * 0.5f;  // even row, even col
    float x3 = xp[1]     * 0.5f;  // even row, odd col
    float x2 = xp[W]     * 0.5f;  // odd row, even col
    float x4 = xp[W + 1] * 0.5f;  // odd row, odd col
    float v[8];
    v[0] =  x1 + x2 + x3 + x4;   // LL
    v[1] = -x1 - x2 + x3 + x4;   // HL
    v[2] = -x1 + x2 - x3 + x4;   // LH
    v[3] =  x1 - x2 - x3 + x4;   // HH
    v[4] =  x1 + x2 - x3 - x4;   // HD
    v[5] = -x1 + x2 + x3 - x4;   // LV
    v[6] =  x1 - x2 + x3 - x4;   // LD
    v[7] = -x1 - x2 - x3 - x4;   // HV
    size_t base = ((size_t)(b * C8 + c) << 14) + i * Wh + j;
    #pragma unroll
    for (int k = 0; k < 8; k++)
        A[base + ((size_t)(k * 64) << 14)] = f2b(v[k]);
}

// ---------------------------------------------------------------- direct conv3x3 (pad=1)
// 16x16 output tile per block, one (b, o). IC chunked by 8 through LDS.
// in: bf16 intermediates, wgt: fp32, out: bf16.
template<int IC, int HW, bool RELU>
__global__ __launch_bounds__(256) void conv3x3_kernel(const bf16* __restrict__ in,
                                                      const float* __restrict__ wgt,
                                                      bf16* __restrict__ out) {
    __shared__ float sIn[8][18][18];
    __shared__ float sW[8][9];
    const int tilesX = HW / 16;
    int tile = blockIdx.x;
    int tX = (tile % tilesX) * 16, tY = (tile / tilesX) * 16;
    int o = blockIdx.y, b = blockIdx.z;
    int OC = gridDim.y;
    int tx = threadIdx.x & 15, ty = threadIdx.x >> 4;
    float acc = 0.f;
    const bf16* inB = in + (size_t)b * IC * HW * HW;
    for (int ic0 = 0; ic0 < IC; ic0 += 8) {
        for (int t = threadIdx.x; t < 8 * 18 * 18; t += 256) {
            int ch = t / 324, rem = t - ch * 324;
            int r = rem / 18, cc = rem - r * 18;
            int gy = tY + r - 1, gx = tX + cc - 1;
            float v = 0.f;
            if (gy >= 0 && gy < HW && gx >= 0 && gx < HW)
                v = b2f(inB[(size_t)(ic0 + ch) * HW * HW + gy * HW + gx]);
            sIn[ch][r][cc] = v;
        }
        if (threadIdx.x < 72) {
            int ch = threadIdx.x / 9, k = threadIdx.x - ch * 9;
            sW[ch][k] = wgt[(size_t)(o * IC + ic0 + ch) * 9 + k];
        }
        __syncthreads();
        #pragma unroll
        for (int ch = 0; ch < 8; ch++)
            #pragma unroll
            for (int dy = 0; dy < 3; dy++)
                #pragma unroll
                for (int dx = 0; dx < 3; dx++)
                    acc += sIn[ch][ty + dy][tx + dx] * sW[ch][dy * 3 + dx];
        __syncthreads();
    }
    if (RELU) acc = fmaxf(acc, 0.f);
    out[((size_t)(b * OC + o) * HW + (tY + ty)) * HW + tX + tx] = f2b(acc);
}

// ---------------------------------------------------------------- sal: channel max/mean pool
__global__ __launch_bounds__(256) void sal_pool_kernel(const bf16* __restrict__ t2,
                                                       float* __restrict__ pool) {
    int p = blockIdx.x * 256 + threadIdx.x;   // B*16384
    int b = p >> 14, px = p & (HWh - 1);
    const bf16* tp = t2 + ((size_t)b * C8 << 14) + px;
    float mx = -1e30f, sm = 0.f;
    for (int c = 0; c < C8; c++) {
        float v = b2f(tp[(size_t)c << 14]);
        mx = fmaxf(mx, v);
        sm += v;
    }
    pool[((size_t)(b * 2) << 14) + px] = mx;
    pool[((size_t)(b * 2 + 1) << 14) + px] = sm * (1.f / 512.f);
}

// ---------------------------------------------------------------- sal: 5x5 conv + sigmoid
__global__ __launch_bounds__(256) void sal_conv_kernel(const float* __restrict__ pool,
                                                       const float* __restrict__ wsal,
                                                       float* __restrict__ smap) {
    int p = blockIdx.x * 256 + threadIdx.x;
    int b = p >> 14, px = p & (HWh - 1);
    int iy = px >> 7, ix = px & 127;
    float acc = 0.f;
    #pragma unroll
    for (int ch = 0; ch < 2; ch++)
        #pragma unroll
        for (int dy = 0; dy < 5; dy++)
            #pragma unroll
            for (int dx = 0; dx < 5; dx++) {
                int gy = iy + dy - 2, gx = ix + dx - 2;
                if (gy >= 0 && gy < Hh && gx >= 0 && gx < Wh)
                    acc += pool[((size_t)(b * 2 + ch) << 14) + gy * Wh + gx] *
                           wsal[ch * 25 + dy * 5 + dx];
            }
    smap[p] = 1.f / (1.f + expf(-acc));
}

// ---------------------------------------------------------------- sal apply + per-channel sums for cal
__global__ __launch_bounds__(256) void sal_mul_sum_kernel(bf16* __restrict__ t2,
                                                          const float* __restrict__ smap,
                                                          float* __restrict__ chsum) {
    int c = blockIdx.x, b = blockIdx.y;
    size_t base = ((size_t)(b * C8 + c) << 14);
    float sm = 0.f;
    #pragma unroll
    for (int k = 0; k < HWh / 256; k++) {
        int px = threadIdx.x + k * 256;
        float v = b2f(t2[base + px]) * smap[(b << 14) + px];
        t2[base + px] = f2b(v);
        sm += v;
    }
    __shared__ float red[256];
    red[threadIdx.x] = sm;
    __syncthreads();
    for (int s = 128; s > 0; s >>= 1) {
        if (threadIdx.x < s) red[threadIdx.x] += red[threadIdx.x + s];
        __syncthreads();
    }
    if (threadIdx.x == 0) chsum[b * C8 + c] = red[0];
}

// ---------------------------------------------------------------- cal MLP -> per (b,c) sigmoid scale
__global__ __launch_bounds__(512) void cal_kernel(const float* __restrict__ chsum,
                                                  const float* __restrict__ wca1,
                                                  const float* __restrict__ wca2,
                                                  float* __restrict__ scale) {
    int b = blockIdx.x;
    __shared__ float sMean[512];
    __shared__ float sH[32];
    sMean[threadIdx.x] = chsum[b * C8 + threadIdx.x] * (1.f / 16384.f);
    __syncthreads();
    if (threadIdx.x < 32) {
        float a = 0.f;
        for (int cc = 0; cc < 512; cc++)
            a += wca1[threadIdx.x * 512 + cc] * sMean[cc];
        sH[threadIdx.x] = fmaxf(a, 0.f);
    }
    __syncthreads();
    float a = 0.f;
    #pragma unroll
    for (int j = 0; j < 32; j++)
        a += wca2[threadIdx.x * 32 + j] * sH[j];
    scale[b * C8 + threadIdx.x] = 1.f / (1.f + expf(-a));
}

// ---------------------------------------------------------------- conv1x1 512->512, cal scale folded
// into weights; adds x_bwt residual, writes A in place. 64 o x 64 px per block, 4x4 per thread.
__global__ __launch_bounds__(256) void conv1x1_kernel(const bf16* __restrict__ t3,
                                                      const float* __restrict__ w1,
                                                      const float* __restrict__ scale,
                                                      bf16* __restrict__ A) {
    __shared__ float sX[32][64];
    __shared__ float sW[64][32];
    int pBase = blockIdx.x * 64;
    int oBase = blockIdx.y * 64;
    int b = blockIdx.z;
    int og = threadIdx.x >> 4, pg = threadIdx.x & 15;
    float acc[4][4] = {};
    for (int ic0 = 0; ic0 < C8; ic0 += 32) {
        #pragma unroll
        for (int k = 0; k < 8; k++) {
            int e = threadIdx.x + k * 256;
            int ic = e >> 6, px = e & 63;
            sX[ic][px] = b2f(t3[(((size_t)(b * C8 + ic0 + ic)) << 14) + pBase + px]);
        }
        #pragma unroll
        for (int k = 0; k < 8; k++) {
            int e = threadIdx.x + k * 256;
            int o = e >> 5, ic = e & 31;
            sW[o][ic] = w1[(size_t)(oBase + o) * C8 + ic0 + ic] * scale[b * C8 + ic0 + ic];
        }
        __syncthreads();
        #pragma unroll
        for (int ic = 0; ic < 32; ic++) {
            float4 xv = *(const float4*)&sX[ic][pg * 4];
            float w0 = sW[og * 4 + 0][ic];
            float wv1 = sW[og * 4 + 1][ic];
            float w2 = sW[og * 4 + 2][ic];
            float w3 = sW[og * 4 + 3][ic];
            acc[0][0] += w0 * xv.x;  acc[0][1] += w0 * xv.y;  acc[0][2] += w0 * xv.z;  acc[0][3] += w0 * xv.w;
            acc[1][0] += wv1 * xv.x; acc[1][1] += wv1 * xv.y; acc[1][2] += wv1 * xv.z; acc[1][3] += wv1 * xv.w;
            acc[2][0] += w2 * xv.x;  acc[2][1] += w2 * xv.y;  acc[2][2] += w2 * xv.z;  acc[2][3] += w2 * xv.w;
            acc[3][0] += w3 * xv.x;  acc[3][1] += w3 * xv.y;  acc[3][2] += w3 * xv.z;  acc[3][3] += w3 * xv.w;
        }
        __syncthreads();
    }
    #pragma unroll
    for (int i = 0; i < 4; i++)
        #pragma unroll
        for (int j = 0; j < 4; j++) {
            size_t idx = (((size_t)(b * C8 + oBase + og * 4 + i)) << 14) + pBase + pg * 4 + j;
            A[idx] = f2b(acc[i][j] + b2f(A[idx]));
        }
}

// ---------------------------------------------------------------- ibwt: (B,512,128,128) -> (B,64,256,256)
__global__ __launch_bounds__(256) void ibwt_kernel(const bf16* __restrict__ A,
                                                   bf16* __restrict__ E) {
    int idx = blockIdx.x * 256 + threadIdx.x;   // B*64*128*128
    int j = idx & 127;
    int i = (idx >> 7) & 127;
    int c = (idx >> 14) & 63;
    int b = idx >> 20;
    size_t base = (((size_t)(b * C8 + c)) << 14) + i * Wh + j;
    float xs[8];
    #pragma unroll
    for (int k = 0; k < 8; k++)
        xs[k] = b2f(A[base + ((size_t)(k * 64) << 14)]) * 0.5f;
    float a00 = xs[0] - xs[1] - xs[2] + xs[3] + xs[4] - xs[5] + xs[6] - xs[7];
    float a10 = xs[0] - xs[1] + xs[2] - xs[3] - xs[4] + xs[5] - xs[6] + xs[7];
    float a01 = xs[0] + xs[1] - xs[2] - xs[3] - xs[4] - xs[5] + xs[6] + xs[7];
    float a11 = xs[0] + xs[1] + xs[2] + xs[3] + xs[4] + xs[5] + xs[6] + xs[7];
    bf16* Ep = E + ((size_t)(b * 64 + c) * H + 2 * i) * W + 2 * j;
    Ep[0] = f2b(a00);
    Ep[1] = f2b(a01);
    Ep[W] = f2b(a10);
    Ep[W + 1] = f2b(a11);
}

// ---------------------------------------------------------------- final: relu(conv3x3(E)) + w_final@x
__global__ __launch_bounds__(256) void final_kernel(const bf16* __restrict__ E,
                                                    const float* __restrict__ w3,
                                                    const float* __restrict__ x,
                                                    const float* __restrict__ wf,
                                                    float* __restrict__ out) {
    __shared__ float sIn[8][18][18];
    __shared__ float sW[8][9];
    const int tilesX = W / 16;
    int tile = blockIdx.x;
    int tX = (tile % tilesX) * 16, tY = (tile / tilesX) * 16;
    int o = blockIdx.y, b = blockIdx.z;
    int tx = threadIdx.x & 15, ty = threadIdx.x >> 4;
    float acc = 0.f;
    const bf16* inB = E + (size_t)b * 64 * HWf;
    for (int ic0 = 0; ic0 < 64; ic0 += 8) {
        for (int t = threadIdx.x; t < 8 * 18 * 18; t += 256) {
            int ch = t / 324, rem = t - ch * 324;
            int r = rem / 18, cc = rem - r * 18;
            int gy = tY + r - 1, gx = tX + cc - 1;
            float v = 0.f;
            if (gy >= 0 && gy < H && gx >= 0 && gx < W)
                v = b2f(inB[(size_t)(ic0 + ch) * HWf + gy * W + gx]);
            sIn[ch][r][cc] = v;
        }
        if (threadIdx.x < 72) {
            int ch = threadIdx.x / 9, k = threadIdx.x - ch * 9;
            sW[ch][k] = w3[(size_t)(o * 64 + ic0 + ch) * 9 + k];
        }
        __syncthreads();
        #pragma unroll
        for (int ch = 0; ch < 8; ch++)
            #pragma unroll
            for (int dy = 0; dy < 3; dy++)
                #pragma unroll
                for (int dx = 0; dx < 3; dx++)
                    acc += sIn[ch][ty + dy][tx + dx] * sW[ch][dy * 3 + dx];
        __syncthreads();
    }
    // 1x1 residual conv over original x (fp32)
    float acc1 = 0.f;
    const float* xB = x + (size_t)(b * 64) * HWf + (tY + ty) * W + tX + tx;
    #pragma unroll 8
    for (int i = 0; i < 64; i++)
        acc1 += xB[(size_t)i * HWf] * wf[o * 64 + i];
    out[((size_t)(b * 64 + o) * H + (tY + ty)) * W + tX + tx] = fmaxf(acc, 0.f) + acc1;
}

// ---------------------------------------------------------------- launch
extern "C" void kernel_launch(void* const* d_in, const int* in_sizes, int n_in,
                              void* d_out, int out_size, void* d_ws, size_t ws_size,
                              hipStream_t stream) {
    const float* x       = (const float*)d_in[0];
    const float* w_body1 = (const float*)d_in[1];
    const float* w_body2 = (const float*)d_in[2];
    const float* w_sal   = (const float*)d_in[3];
    const float* w_ca1   = (const float*)d_in[4];
    const float* w_ca2   = (const float*)d_in[5];
    const float* w_1x1   = (const float*)d_in[6];
    const float* w_3x3   = (const float*)d_in[7];
    const float* w_final = (const float*)d_in[8];

    char* ws = (char*)d_ws;
    bf16*  A     = (bf16*)(ws + 0);            // 67,108,864 B  (x_bwt, later t4 in place)
    bf16*  T2    = (bf16*)(ws + 67108864);     // 67,108,864 B  (body2 out / sal-cal in place)
    bf16*  T1    = (bf16*)(ws + 134217728);    //  8,388,608 B  (body1 out)
    float* pool  = (float*)(ws + 142606336);   //    524,288 B
    float* smap  = (float*)(ws + 143130624);   //    262,144 B
    float* chsum = (float*)(ws + 143392768);   //      8,192 B
    float* scale = (float*)(ws + 143400960);   //      8,192 B
    bf16*  E     = T2;                         // T2 dead after conv1x1; ibwt output aliases it

    bwt_kernel<<<16384, 256, 0, stream>>>(x, A);
    conv3x3_kernel<512, 128, true ><<<dim3(64, 64, 4),  256, 0, stream>>>(A,  w_body1, T1);
    conv3x3_kernel<64,  128, false><<<dim3(64, 512, 4), 256, 0, stream>>>(T1, w_body2, T2);
    sal_pool_kernel<<<256, 256, 0, stream>>>(T2, pool);
    sal_conv_kernel<<<256, 256, 0, stream>>>(pool, w_sal, smap);
    sal_mul_sum_kernel<<<dim3(512, 4), 256, 0, stream>>>(T2, smap, chsum);
    cal_kernel<<<4, 512, 0, stream>>>(chsum, w_ca1, w_ca2, scale);
    conv1x1_kernel<<<dim3(256, 8, 4), 256, 0, stream>>>(T2, w_1x1, scale, A);
    ibwt_kernel<<<16384, 256, 0, stream>>>(A, E);
    final_kernel<<<dim3(256, 64, 4), 256, 0, stream>>>(E, w_3x3, x, w_final, (float*)d_out);
}

// Round 3
// 521.914 us; speedup vs baseline: 18.2395x; 18.2395x over previous
//
#include <hip/hip_runtime.h>
#include <hip/hip_bf16.h>

typedef __hip_bfloat16 bf16;
using short8  = __attribute__((ext_vector_type(8))) short;
using floatx4 = __attribute__((ext_vector_type(4))) float;

__device__ __forceinline__ float b2f(bf16 v) { return __bfloat162float(v); }
__device__ __forceinline__ bf16 f2b(float v) { return __float2bfloat16(v); }
__device__ __forceinline__ float s2f(short s) {
    return __uint_as_float(((unsigned)(unsigned short)s) << 16);
}

constexpr int Bz = 4, H = 256, W = 256, Hh = 128, Wh = 128, C8 = 512;
constexpr int HWh = Hh * Wh;   // 16384
constexpr int HWf = H * W;     // 65536
constexpr int ICP = 40;        // LDS ic stride (32 + 8 pad): lane stride 20 words -> 2-way (free)

// ---------------------------------------------------------------- weight reorder: (OC,IC,3,3) fp32 -> [tap][oc][ic] bf16
template<int OC, int IC>
__global__ __launch_bounds__(256) void prep_wr(const float* __restrict__ w, bf16* __restrict__ wr) {
    int idx = blockIdx.x * 256 + threadIdx.x;
    if (idx >= 9 * OC * IC) return;
    int ic = idx & (IC - 1);
    int oc = (idx / IC) & (OC - 1);
    int tap = idx / (IC * OC);
    wr[idx] = f2b(w[(oc * IC + ic) * 9 + tap]);
}

__global__ __launch_bounds__(256) void prep_wfr(const float* __restrict__ wf, bf16* __restrict__ wfr) {
    int idx = blockIdx.x * 256 + threadIdx.x;   // 64*64
    wfr[idx] = f2b(wf[idx]);
}

// w1s[b][oc][ic] = w_1x1[oc][ic] * cal_scale[b][ic]
__global__ __launch_bounds__(256) void prep_w1s(const float* __restrict__ w1,
                                                const float* __restrict__ scale,
                                                bf16* __restrict__ w1s) {
    int idx = blockIdx.x * 256 + threadIdx.x;   // 4*512*512
    int ic = idx & 511, oc = (idx >> 9) & 511, b = idx >> 18;
    w1s[idx] = f2b(w1[oc * 512 + ic] * scale[b * 512 + ic]);
}

// ---------------------------------------------------------------- bwt: x NCHW fp32 -> A NHWC bf16 (B,128,128,512)
__global__ __launch_bounds__(256) void bwt_nhwc(const float* __restrict__ x, bf16* __restrict__ A) {
    int idx = blockIdx.x * 256 + threadIdx.x;   // (b,i,j,c) c fast
    int c = idx & 63;
    int j = (idx >> 6) & 127;
    int i = (idx >> 13) & 127;
    int b = idx >> 20;
    const float* xp = x + ((size_t)(b * 64 + c) * H + 2 * i) * W + 2 * j;
    float2 ev = *(const float2*)xp;         // even row: x1, x3
    float2 od = *(const float2*)(xp + W);   // odd row:  x2, x4
    float x1 = ev.x * 0.5f, x3 = ev.y * 0.5f, x2 = od.x * 0.5f, x4 = od.y * 0.5f;
    float v[8];
    v[0] =  x1 + x2 + x3 + x4;
    v[1] = -x1 - x2 + x3 + x4;
    v[2] = -x1 + x2 - x3 + x4;
    v[3] =  x1 - x2 - x3 + x4;
    v[4] =  x1 + x2 - x3 - x4;
    v[5] = -x1 + x2 + x3 - x4;
    v[6] =  x1 - x2 + x3 - x4;
    v[7] = -x1 - x2 - x3 - x4;
    size_t base = (size_t)(idx >> 6) * 512 + c;   // pixel*512 + c
    #pragma unroll
    for (int k = 0; k < 8; k++)
        A[base + k * 64] = f2b(v[k]);
}

// ---------------------------------------------------------------- conv3x3 MFMA implicit GEMM, NHWC
// Block: TRx16 spatial tile x 64 oc. 4 waves; wave = TR/4... (MT=TR/4 rows) x 4 ntiles.
// K = IC x 9 taps, chunks of 32 ic; taps via shifted reads of haloed LDS tile.
template<int IC, int OC, int HW, int TR, bool RELU>
__global__ __launch_bounds__(256, 2) void conv3x3_mfma(const bf16* __restrict__ in,
                                                       const bf16* __restrict__ wr,
                                                       bf16* __restrict__ out) {
    constexpr int MT = TR / 4;                       // mtiles (rows) per wave
    __shared__ bf16 sIn[(TR + 2) * 18 * ICP];
    __shared__ bf16 sW3[3 * 64 * ICP];               // 3 taps (one dy) x 64 oc x 32 ic

    const int tilesX = HW / 16;
    int tX = (blockIdx.x % tilesX) * 16;
    int tY = (blockIdx.x / tilesX) * TR;
    int oBase = blockIdx.y * 64;
    int b = blockIdx.z;
    int tid = threadIdx.x;
    int lane = tid & 63, wid = tid >> 6;
    int m = lane & 15, quad = lane >> 4;

    floatx4 acc[MT][4];
    #pragma unroll
    for (int i = 0; i < MT; i++)
        #pragma unroll
        for (int j = 0; j < 4; j++)
            acc[i][j] = (floatx4){0.f, 0.f, 0.f, 0.f};

    const bf16* inB = in + (size_t)b * HW * HW * IC;

    for (int ic0 = 0; ic0 < IC; ic0 += 32) {
        __syncthreads();
        // stage haloed input tile: (TR+2) x 18 cells x 32 ic, 16B per thread-iter
        for (int e = tid; e < (TR + 2) * 18 * 4; e += 256) {
            int q = e & 3, cell = e >> 2;
            int r = cell / 18, c = cell - r * 18;
            int gr = tY + r - 1, gc = tX + c - 1;
            short8 v = {0, 0, 0, 0, 0, 0, 0, 0};
            if (gr >= 0 && gr < HW && gc >= 0 && gc < HW)
                v = *(const short8*)(inB + (size_t)(gr * HW + gc) * IC + ic0 + q * 8);
            *(short8*)(sIn + cell * ICP + q * 8) = v;
        }
        for (int dy = 0; dy < 3; dy++) {
            if (dy) __syncthreads();
            // stage 3 taps of weights (dy fixed): 192 rows x 4 chunks
            for (int e = tid; e < 768; e += 256) {
                int q = e & 3, row = e >> 2;         // row = dx*64 + oc
                int dxl = row >> 6, oc = row & 63;
                int tap = dy * 3 + dxl;
                short8 v = *(const short8*)(wr + (size_t)(tap * OC + oBase + oc) * IC + ic0 + q * 8);
                *(short8*)(sW3 + row * ICP + q * 8) = v;
            }
            __syncthreads();
            #pragma unroll
            for (int dx = 0; dx < 3; dx++) {
                short8 bfr[4];
                #pragma unroll
                for (int nt = 0; nt < 4; nt++)
                    bfr[nt] = *(const short8*)(sW3 + (dx * 64 + nt * 16 + m) * ICP + quad * 8);
                #pragma unroll
                for (int mt = 0; mt < MT; mt++) {
                    int r = wid * MT + mt;
                    short8 afr = *(const short8*)(sIn + ((r + dy) * 18 + m + dx) * ICP + quad * 8);
                    #pragma unroll
                    for (int nt = 0; nt < 4; nt++)
                        acc[mt][nt] = __builtin_amdgcn_mfma_f32_16x16x32_bf16(afr, bfr[nt], acc[mt][nt], 0, 0, 0);
                }
            }
        }
    }
    // epilogue: D[m=pixel-col][n=oc], lane: col = quad*4+reg, oc = nt*16 + (lane&15)
    #pragma unroll
    for (int mt = 0; mt < MT; mt++) {
        int row = tY + wid * MT + mt;
        #pragma unroll
        for (int nt = 0; nt < 4; nt++) {
            int oc = oBase + nt * 16 + m;
            #pragma unroll
            for (int reg = 0; reg < 4; reg++) {
                int col = tX + quad * 4 + reg;
                float v = acc[mt][nt][reg];
                if (RELU) v = fmaxf(v, 0.f);
                out[((size_t)(b * HW + row) * HW + col) * OC + oc] = f2b(v);
            }
        }
    }
}

// ---------------------------------------------------------------- conv1x1 MFMA: t3 NHWC x w1s[b] -> + A residual, into A
__global__ __launch_bounds__(256, 2) void conv1x1_mfma(const bf16* __restrict__ t3,
                                                       const bf16* __restrict__ w1s,
                                                       bf16* __restrict__ A) {
    __shared__ bf16 sX[256 * ICP];
    __shared__ bf16 sW1[64 * ICP];
    int p0 = blockIdx.x * 256;
    int oBase = blockIdx.y * 64;
    int b = blockIdx.z;
    int tid = threadIdx.x;
    int lane = tid & 63, wid = tid >> 6;
    int m = lane & 15, quad = lane >> 4;
    const bf16* wB = w1s + (size_t)b * 512 * 512;
    const bf16* tB = t3 + ((size_t)b << 14) * 512;

    floatx4 acc[4][4];
    #pragma unroll
    for (int i = 0; i < 4; i++)
        #pragma unroll
        for (int j = 0; j < 4; j++)
            acc[i][j] = (floatx4){0.f, 0.f, 0.f, 0.f};

    for (int ic0 = 0; ic0 < 512; ic0 += 32) {
        __syncthreads();
        #pragma unroll
        for (int k = 0; k < 4; k++) {
            int e = tid + k * 256;            // 1024 = 256 pix x 4 chunks
            int q = e & 3, p = e >> 2;
            *(short8*)(sX + p * ICP + q * 8) =
                *(const short8*)(tB + (size_t)(p0 + p) * 512 + ic0 + q * 8);
        }
        {
            int q = tid & 3, oc = tid >> 2;   // 256 threads = 64 oc x 4 chunks
            *(short8*)(sW1 + oc * ICP + q * 8) =
                *(const short8*)(wB + (size_t)(oBase + oc) * 512 + ic0 + q * 8);
        }
        __syncthreads();
        short8 bfr[4];
        #pragma unroll
        for (int nt = 0; nt < 4; nt++)
            bfr[nt] = *(const short8*)(sW1 + (nt * 16 + m) * ICP + quad * 8);
        #pragma unroll
        for (int mt = 0; mt < 4; mt++) {
            short8 afr = *(const short8*)(sX + ((wid * 4 + mt) * 16 + m) * ICP + quad * 8);
            #pragma unroll
            for (int nt = 0; nt < 4; nt++)
                acc[mt][nt] = __builtin_amdgcn_mfma_f32_16x16x32_bf16(afr, bfr[nt], acc[mt][nt], 0, 0, 0);
        }
    }
    bf16* AB = A + ((size_t)b << 14) * 512;
    #pragma unroll
    for (int mt = 0; mt < 4; mt++) {
        #pragma unroll
        for (int nt = 0; nt < 4; nt++) {
            int oc = oBase + nt * 16 + m;
            #pragma unroll
            for (int reg = 0; reg < 4; reg++) {
                int p = p0 + (wid * 4 + mt) * 16 + quad * 4 + reg;
                size_t a = (size_t)p * 512 + oc;
                AB[a] = f2b(acc[mt][nt][reg] + b2f(AB[a]));
            }
        }
    }
}

// ---------------------------------------------------------------- sal: per-pixel channel max/mean (NHWC: one wave/pixel)
__global__ __launch_bounds__(256) void sal_pool(const bf16* __restrict__ t2, float* __restrict__ pool) {
    int pix = blockIdx.x * 4 + (threadIdx.x >> 6);   // 0..65535
    int lane = threadIdx.x & 63;
    short8 v = *(const short8*)(t2 + (size_t)pix * 512 + lane * 8);
    float mx = -1e30f, sm = 0.f;
    #pragma unroll
    for (int i = 0; i < 8; i++) {
        float f = s2f(v[i]);
        mx = fmaxf(mx, f);
        sm += f;
    }
    #pragma unroll
    for (int off = 32; off > 0; off >>= 1) {
        mx = fmaxf(mx, __shfl_xor(mx, off));
        sm += __shfl_xor(sm, off);
    }
    if (lane == 0) {
        int b = pix >> 14, px = pix & (HWh - 1);
        pool[((size_t)(b * 2) << 14) + px] = mx;
        pool[((size_t)(b * 2 + 1) << 14) + px] = sm * (1.f / 512.f);
    }
}

// ---------------------------------------------------------------- sal: 5x5 conv + sigmoid
__global__ __launch_bounds__(256) void sal_conv(const float* __restrict__ pool,
                                                const float* __restrict__ wsal,
                                                float* __restrict__ smap) {
    int p = blockIdx.x * 256 + threadIdx.x;
    int b = p >> 14, px = p & (HWh - 1);
    int iy = px >> 7, ix = px & 127;
    float acc = 0.f;
    #pragma unroll
    for (int ch = 0; ch < 2; ch++)
        #pragma unroll
        for (int dy = 0; dy < 5; dy++)
            #pragma unroll
            for (int dx = 0; dx < 5; dx++) {
                int gy = iy + dy - 2, gx = ix + dx - 2;
                if (gy >= 0 && gy < Hh && gx >= 0 && gx < Wh)
                    acc += pool[((size_t)(b * 2 + ch) << 14) + gy * Wh + gx] *
                           wsal[ch * 25 + dy * 5 + dx];
            }
    smap[p] = 1.f / (1.f + expf(-acc));
}

// ---------------------------------------------------------------- sal apply (in place) + channel sums via atomics
__global__ __launch_bounds__(256) void sal_mul_sum(bf16* __restrict__ t2,
                                                   const float* __restrict__ smap,
                                                   float* __restrict__ chsum) {
    int b = blockIdx.y;
    int p0 = blockIdx.x * 32;
    int t = threadIdx.x;                       // channels 2t, 2t+1
    float s0 = 0.f, s1 = 0.f;
    bf16* tB = t2 + ((size_t)b << 14) * 512;
    #pragma unroll 4
    for (int k = 0; k < 32; k++) {
        int pix = p0 + k;
        float sc = smap[(b << 14) + pix];
        size_t base = (size_t)pix * 512 + 2 * t;
        float f0 = b2f(tB[base]) * sc;
        float f1 = b2f(tB[base + 1]) * sc;
        tB[base] = f2b(f0);
        tB[base + 1] = f2b(f1);
        s0 += f0; s1 += f1;
    }
    atomicAdd(&chsum[b * 512 + 2 * t], s0);
    atomicAdd(&chsum[b * 512 + 2 * t + 1], s1);
}

// ---------------------------------------------------------------- cal MLP -> sigmoid scale per (b,c)
__global__ __launch_bounds__(512) void cal_kernel(const float* __restrict__ chsum,
                                                  const float* __restrict__ wca1,
                                                  const float* __restrict__ wca2,
                                                  float* __restrict__ scale) {
    int b = blockIdx.x;
    __shared__ float sMean[512];
    __shared__ float sH[32];
    sMean[threadIdx.x] = chsum[b * C8 + threadIdx.x] * (1.f / 16384.f);
    __syncthreads();
    if (threadIdx.x < 32) {
        float a = 0.f;
        for (int cc = 0; cc < 512; cc++)
            a += wca1[threadIdx.x * 512 + cc] * sMean[cc];
        sH[threadIdx.x] = fmaxf(a, 0.f);
    }
    __syncthreads();
    float a = 0.f;
    #pragma unroll
    for (int j = 0; j < 32; j++)
        a += wca2[threadIdx.x * 32 + j] * sH[j];
    scale[b * C8 + threadIdx.x] = 1.f / (1.f + expf(-a));
}

// ---------------------------------------------------------------- ibwt: A NHWC (B,128,128,512) -> E NHWC (B,256,256,64)
__global__ __launch_bounds__(256) void ibwt_nhwc(const bf16* __restrict__ A, bf16* __restrict__ E) {
    int idx = blockIdx.x * 256 + threadIdx.x;
    int c = idx & 63;
    int j = (idx >> 6) & 127;
    int i = (idx >> 13) & 127;
    int b = idx >> 20;
    size_t base = (size_t)(idx >> 6) * 512 + c;
    float xs[8];
    #pragma unroll
    for (int k = 0; k < 8; k++)
        xs[k] = b2f(A[base + k * 64]) * 0.5f;
    float a00 = xs[0] - xs[1] - xs[2] + xs[3] + xs[4] - xs[5] + xs[6] - xs[7];
    float a10 = xs[0] - xs[1] + xs[2] - xs[3] - xs[4] + xs[5] - xs[6] + xs[7];
    float a01 = xs[0] + xs[1] - xs[2] - xs[3] - xs[4] - xs[5] + xs[6] + xs[7];
    float a11 = xs[0] + xs[1] + xs[2] + xs[3] + xs[4] + xs[5] + xs[6] + xs[7];
    bf16* Ep = E + ((size_t)((b * H + 2 * i) * W + 2 * j)) * 64 + c;
    Ep[0]          = f2b(a00);
    Ep[64]         = f2b(a01);
    Ep[W * 64]     = f2b(a10);
    Ep[W * 64 + 64] = f2b(a11);
}

// ---------------------------------------------------------------- final: relu(conv3x3(E)) + w_final@x -> NCHW fp32
__global__ __launch_bounds__(256, 2) void final_mfma(const bf16* __restrict__ E,
                                                     const bf16* __restrict__ wr3,
                                                     const float* __restrict__ x,
                                                     const bf16* __restrict__ wfr,
                                                     float* __restrict__ out) {
    __shared__ bf16 sIn[18 * 18 * ICP];
    __shared__ bf16 sW3[3 * 64 * ICP];
    const int tilesX = W / 16;
    int tX = (blockIdx.x % tilesX) * 16;
    int tY = (blockIdx.x / tilesX) * 16;
    int b = blockIdx.z;
    int tid = threadIdx.x;
    int lane = tid & 63, wid = tid >> 6;
    int m = lane & 15, quad = lane >> 4;

    floatx4 acc[4][4];
    #pragma unroll
    for (int i = 0; i < 4; i++)
        #pragma unroll
        for (int j = 0; j < 4; j++)
            acc[i][j] = (floatx4){0.f, 0.f, 0.f, 0.f};

    const bf16* inB = E + (size_t)b * HWf * 64;
    // phase 1: 3x3 over E, IC=64
    for (int ic0 = 0; ic0 < 64; ic0 += 32) {
        __syncthreads();
        for (int e = tid; e < 18 * 18 * 4; e += 256) {
            int q = e & 3, cell = e >> 2;
            int r = cell / 18, c = cell - r * 18;
            int gr = tY + r - 1, gc = tX + c - 1;
            short8 v = {0, 0, 0, 0, 0, 0, 0, 0};
            if (gr >= 0 && gr < H && gc >= 0 && gc < W)
                v = *(const short8*)(inB + (size_t)(gr * W + gc) * 64 + ic0 + q * 8);
            *(short8*)(sIn + cell * ICP + q * 8) = v;
        }
        for (int dy = 0; dy < 3; dy++) {
            if (dy) __syncthreads();
            for (int e = tid; e < 768; e += 256) {
                int q = e & 3, row = e >> 2;
                int dxl = row >> 6, oc = row & 63;
                int tap = dy * 3 + dxl;
                short8 v = *(const short8*)(wr3 + (size_t)(tap * 64 + oc) * 64 + ic0 + q * 8);
                *(short8*)(sW3 + row * ICP + q * 8) = v;
            }
            __syncthreads();
            #pragma unroll
            for (int dx = 0; dx < 3; dx++) {
                short8 bfr[4];
                #pragma unroll
                for (int nt = 0; nt < 4; nt++)
                    bfr[nt] = *(const short8*)(sW3 + (dx * 64 + nt * 16 + m) * ICP + quad * 8);
                #pragma unroll
                for (int mt = 0; mt < 4; mt++) {
                    int r = wid * 4 + mt;
                    short8 afr = *(const short8*)(sIn + ((r + dy) * 18 + m + dx) * ICP + quad * 8);
                    #pragma unroll
                    for (int nt = 0; nt < 4; nt++)
                        acc[mt][nt] = __builtin_amdgcn_mfma_f32_16x16x32_bf16(afr, bfr[nt], acc[mt][nt], 0, 0, 0);
                }
            }
        }
    }
    // relu the 3x3 part only
    #pragma unroll
    for (int i = 0; i < 4; i++)
        #pragma unroll
        for (int j = 0; j < 4; j++)
            #pragma unroll
            for (int r = 0; r < 4; r++)
                acc[i][j][r] = fmaxf(acc[i][j][r], 0.f);

    // phase 2: + 1x1(x), x NCHW fp32 staged into halo-center, single tap (dy=1,dx=1)
    for (int icc = 0; icc < 64; icc += 32) {
        __syncthreads();
        for (int e = tid; e < 2048; e += 256) {       // 32 ic x 16 r x 4 col-quads
            int c4 = e & 3, r = (e >> 2) & 15, ic = e >> 6;
            float4 v = *(const float4*)(x + ((size_t)(b * 64 + icc + ic) * H + tY + r) * W + tX + c4 * 4);
            bf16* dst = sIn + ((r + 1) * 18 + c4 * 4 + 1) * ICP + ic;
            dst[0]       = f2b(v.x);
            dst[ICP]     = f2b(v.y);
            dst[2 * ICP] = f2b(v.z);
            dst[3 * ICP] = f2b(v.w);
        }
        {
            int q = tid & 3, oc = tid >> 2;           // 64 oc x 4 chunks -> tap-slot 1
            *(short8*)(sW3 + (64 + oc) * ICP + q * 8) =
                *(const short8*)(wfr + oc * 64 + icc + q * 8);
        }
        __syncthreads();
        short8 bfr[4];
        #pragma unroll
        for (int nt = 0; nt < 4; nt++)
            bfr[nt] = *(const short8*)(sW3 + (64 + nt * 16 + m) * ICP + quad * 8);
        #pragma unroll
        for (int mt = 0; mt < 4; mt++) {
            int r = wid * 4 + mt;
            short8 afr = *(const short8*)(sIn + ((r + 1) * 18 + m + 1) * ICP + quad * 8);
            #pragma unroll
            for (int nt = 0; nt < 4; nt++)
                acc[mt][nt] = __builtin_amdgcn_mfma_f32_16x16x32_bf16(afr, bfr[nt], acc[mt][nt], 0, 0, 0);
        }
    }
    // write NCHW fp32, float4 per (mt, nt)
    #pragma unroll
    for (int mt = 0; mt < 4; mt++) {
        int gr = tY + wid * 4 + mt;
        #pragma unroll
        for (int nt = 0; nt < 4; nt++) {
            int oc = nt * 16 + m;
            *(floatx4*)(out + ((size_t)(b * 64 + oc) * H + gr) * W + tX + quad * 4) = acc[mt][nt];
        }
    }
}

// ---------------------------------------------------------------- launch
extern "C" void kernel_launch(void* const* d_in, const int* in_sizes, int n_in,
                              void* d_out, int out_size, void* d_ws, size_t ws_size,
                              hipStream_t stream) {
    const float* x       = (const float*)d_in[0];
    const float* w_body1 = (const float*)d_in[1];
    const float* w_body2 = (const float*)d_in[2];
    const float* w_sal   = (const float*)d_in[3];
    const float* w_ca1   = (const float*)d_in[4];
    const float* w_ca2   = (const float*)d_in[5];
    const float* w_1x1   = (const float*)d_in[6];
    const float* w_3x3   = (const float*)d_in[7];
    const float* w_final = (const float*)d_in[8];

    char* ws = (char*)d_ws;
    bf16*  A     = (bf16*)(ws + 0);            // 67,108,864  NHWC (B,128,128,512): x_bwt, later conv1x1 out
    bf16*  T2    = (bf16*)(ws + 67108864);     // 67,108,864  NHWC body2 out; later E aliases it
    // T1 region (8,388,608): live only between body1 and body2; small buffers live after
    bf16*  T1    = (bf16*)(ws + 134217728);
    float* pool  = (float*)(ws + 134217728);   //   524,288 (after body2, T1 dead)
    float* smap  = (float*)(ws + 134742016);   //   262,144
    float* chsum = (float*)(ws + 135004160);   //     8,192
    float* scale = (float*)(ws + 135012352);   //     8,192
    bf16*  w1s   = (bf16*)(ws + 135020544);    // 2,097,152
    bf16*  wr3   = (bf16*)(ws + 137117696);    //    73,728
    bf16*  wfr   = (bf16*)(ws + 137191424);    //     8,192
    bf16*  E     = T2;
    // wr1/wr2 parked in d_out (dead until final_mfma writes it)
    bf16*  wr1   = (bf16*)d_out;               //   589,824
    bf16*  wr2   = (bf16*)((char*)d_out + 589824);

    prep_wr<64, 512><<<1152, 256, 0, stream>>>(w_body1, wr1);
    prep_wr<512, 64><<<1152, 256, 0, stream>>>(w_body2, wr2);
    bwt_nhwc<<<16384, 256, 0, stream>>>(x, A);
    conv3x3_mfma<512, 64, 128, 8, true ><<<dim3(128, 1, 4), 256, 0, stream>>>(A, wr1, T1);
    conv3x3_mfma<64, 512, 128, 16, false><<<dim3(64, 8, 4), 256, 0, stream>>>(T1, wr2, T2);
    sal_pool<<<16384, 256, 0, stream>>>(T2, pool);
    sal_conv<<<256, 256, 0, stream>>>(pool, w_sal, smap);
    hipMemsetAsync(chsum, 0, 4 * 512 * sizeof(float), stream);
    sal_mul_sum<<<dim3(512, 4), 256, 0, stream>>>(T2, smap, chsum);
    cal_kernel<<<4, 512, 0, stream>>>(chsum, w_ca1, w_ca2, scale);
    prep_w1s<<<4096, 256, 0, stream>>>(w_1x1, scale, w1s);
    prep_wr<64, 64><<<144, 256, 0, stream>>>(w_3x3, wr3);
    prep_wfr<<<16, 256, 0, stream>>>(w_final, wfr);
    conv1x1_mfma<<<dim3(64, 8, 4), 256, 0, stream>>>(T2, w1s, A);
    ibwt_nhwc<<<16384, 256, 0, stream>>>(A, E);
    final_mfma<<<dim3(256, 1, 4), 256, 0, stream>>>(E, wr3, x, wfr, (float*)d_out);
}

// Round 4
// 478.684 us; speedup vs baseline: 19.8868x; 1.0903x over previous
//
#include <hip/hip_runtime.h>
#include <hip/hip_bf16.h>

typedef __hip_bfloat16 bf16;
using short8  = __attribute__((ext_vector_type(8))) short;
using floatx4 = __attribute__((ext_vector_type(4))) float;

__device__ __forceinline__ float b2f(bf16 v) { return __bfloat162float(v); }
__device__ __forceinline__ bf16 f2b(float v) { return __float2bfloat16(v); }
__device__ __forceinline__ float s2f(short s) {
    return __uint_as_float(((unsigned)(unsigned short)s) << 16);
}
__device__ __forceinline__ unsigned short fbits(float v) {
    bf16 b = f2b(v);
    return *(unsigned short*)&b;
}

constexpr int H = 256, W = 256, Hh = 128, Wh = 128, C8 = 512;
constexpr int HWh = Hh * Wh;   // 16384
constexpr int HWf = H * W;     // 65536
constexpr int ICP = 40;        // LDS ic stride (32+8 pad): lane stride 20 words -> 2-way (free)

// ---------------------------------------------------------------- weight reorder
template<int OC, int IC>
__global__ __launch_bounds__(256) void prep_wr(const float* __restrict__ w, bf16* __restrict__ wr) {
    int idx = blockIdx.x * 256 + threadIdx.x;
    if (idx >= 9 * OC * IC) return;
    int ic = idx & (IC - 1);
    int oc = (idx / IC) & (OC - 1);
    int tap = idx / (IC * OC);
    wr[idx] = f2b(w[(oc * IC + ic) * 9 + tap]);
}

__global__ __launch_bounds__(256) void prep_wfr(const float* __restrict__ wf, bf16* __restrict__ wfr) {
    int idx = blockIdx.x * 256 + threadIdx.x;   // 64*64
    wfr[idx] = f2b(wf[idx]);
}

// w1s[b][oc][ic] = w_1x1[oc][ic] * cal_scale[b][ic]
__global__ __launch_bounds__(256) void prep_w1s(const float* __restrict__ w1,
                                                const float* __restrict__ scale,
                                                bf16* __restrict__ w1s) {
    int idx = blockIdx.x * 256 + threadIdx.x;   // 4*512*512
    int ic = idx & 511, oc = (idx >> 9) & 511, b = idx >> 18;
    w1s[idx] = f2b(w1[oc * 512 + ic] * scale[b * 512 + ic]);
}

// ---------------------------------------------------------------- bwt, LDS-transposed
// block: one (b, i, half-row of 64 j), all 64 c. Coalesced x loads, contiguous NHWC stores.
constexpr int XROW = 130;  // LDS row stride in halfwords (stride 65 words -> conflict-free reads)
__global__ __launch_bounds__(256, 2) void bwt_nhwc(const float* __restrict__ x, bf16* __restrict__ A) {
    __shared__ unsigned short sX[2 * 64 * XROW];
    int bx = blockIdx.x;           // 0..255: i = bx>>1, jh = bx&1
    int i = bx >> 1, j0 = (bx & 1) * 64;
    int b = blockIdx.z;
    int tid = threadIdx.x;
    // load: 64 c x 2 rows x 128 w (float4 units: 64*2*32 = 4096)
    for (int k = 0; k < 16; k++) {
        int e = tid + k * 256;
        int w4 = e & 31, r = (e >> 5) & 1, c = e >> 6;
        float4 v = *(const float4*)(x + (((size_t)(b * 64 + c) * H + 2 * i + r) * W) + j0 * 2 + w4 * 4);
        unsigned lo = ((unsigned)fbits(v.y) << 16) | fbits(v.x);
        unsigned hi = ((unsigned)fbits(v.w) << 16) | fbits(v.z);
        unsigned short* dst = sX + (r * 64 + c) * XROW + w4 * 4;
        *(unsigned*)(dst) = lo;
        *(unsigned*)(dst + 2) = hi;
    }
    __syncthreads();
    int c = tid & 63, wid = tid >> 6;
    for (int k = 0; k < 16; k++) {
        int jr = wid * 16 + k;
        unsigned ev = *(const unsigned*)(sX + c * XROW + jr * 2);
        unsigned od = *(const unsigned*)(sX + (64 + c) * XROW + jr * 2);
        float x1 = s2f((short)(ev & 0xffff)) * 0.5f;
        float x3 = s2f((short)(ev >> 16)) * 0.5f;
        float x2 = s2f((short)(od & 0xffff)) * 0.5f;
        float x4 = s2f((short)(od >> 16)) * 0.5f;
        float v[8];
        v[0] =  x1 + x2 + x3 + x4;
        v[1] = -x1 - x2 + x3 + x4;
        v[2] = -x1 + x2 - x3 + x4;
        v[3] =  x1 - x2 - x3 + x4;
        v[4] =  x1 + x2 - x3 - x4;
        v[5] = -x1 + x2 + x3 - x4;
        v[6] =  x1 - x2 + x3 - x4;
        v[7] = -x1 - x2 - x3 - x4;
        size_t base = ((size_t)((b * Hh + i) * Wh) + j0 + jr) * 512 + c;
        #pragma unroll
        for (int band = 0; band < 8; band++)
            A[base + band * 64] = f2b(v[band]);
    }
}

// ---------------------------------------------------------------- conv3x3 MFMA implicit GEMM, NHWC
// 16x16 spatial tile x 64 oc; 4 waves; wave = 4 rows (64 px) x 64 oc. All 9 taps staged per ic-chunk.
template<int IC, int OC, int HW, bool RELU, int MINW>
__global__ __launch_bounds__(256, MINW) void conv3x3_mfma(const bf16* __restrict__ in,
                                                          const bf16* __restrict__ wr,
                                                          bf16* __restrict__ out) {
    __shared__ bf16 sIn[18 * 18 * ICP];
    __shared__ bf16 sW9[9 * 64 * ICP];

    const int tilesX = HW / 16;
    int tX = (blockIdx.x % tilesX) * 16;
    int tY = (blockIdx.x / tilesX) * 16;
    int oBase = blockIdx.y * 64;
    int b = blockIdx.z;
    int tid = threadIdx.x;
    int lane = tid & 63, wid = tid >> 6;
    int m = lane & 15, quad = lane >> 4;

    floatx4 acc[4][4];
    #pragma unroll
    for (int i = 0; i < 4; i++)
        #pragma unroll
        for (int j = 0; j < 4; j++)
            acc[i][j] = (floatx4){0.f, 0.f, 0.f, 0.f};

    const bf16* inB = in + (size_t)b * HW * HW * IC;

    for (int ic0 = 0; ic0 < IC; ic0 += 32) {
        __syncthreads();
        // input tile: 18x18 cells x 32 ic (4 chunks of 8)
        for (int e = tid; e < 18 * 18 * 4; e += 256) {
            int q = e & 3, cell = e >> 2;
            int r = cell / 18, c = cell - r * 18;
            int gr = tY + r - 1, gc = tX + c - 1;
            short8 v = {0, 0, 0, 0, 0, 0, 0, 0};
            if (gr >= 0 && gr < HW && gc >= 0 && gc < HW)
                v = *(const short8*)(inB + (size_t)(gr * HW + gc) * IC + ic0 + q * 8);
            *(short8*)(sIn + cell * ICP + q * 8) = v;
        }
        // all 9 taps of weights: 576 rows x 4 chunks
        for (int e = tid; e < 2304; e += 256) {
            int q = e & 3, row = e >> 2;         // row = tap*64 + oc
            int tap = row >> 6, oc = row & 63;
            short8 v = *(const short8*)(wr + (size_t)(tap * OC + oBase + oc) * IC + ic0 + q * 8);
            *(short8*)(sW9 + row * ICP + q * 8) = v;
        }
        __syncthreads();
        #pragma unroll
        for (int dy = 0; dy < 3; dy++) {
            #pragma unroll
            for (int dx = 0; dx < 3; dx++) {
                short8 bfr[4];
                #pragma unroll
                for (int nt = 0; nt < 4; nt++)
                    bfr[nt] = *(const short8*)(sW9 + ((dy * 3 + dx) * 64 + nt * 16 + m) * ICP + quad * 8);
                #pragma unroll
                for (int mt = 0; mt < 4; mt++) {
                    int r = wid * 4 + mt;
                    short8 afr = *(const short8*)(sIn + ((r + dy) * 18 + m + dx) * ICP + quad * 8);
                    #pragma unroll
                    for (int nt = 0; nt < 4; nt++)
                        acc[mt][nt] = __builtin_amdgcn_mfma_f32_16x16x32_bf16(afr, bfr[nt], acc[mt][nt], 0, 0, 0);
                }
            }
        }
    }
    #pragma unroll
    for (int mt = 0; mt < 4; mt++) {
        int row = tY + wid * 4 + mt;
        #pragma unroll
        for (int nt = 0; nt < 4; nt++) {
            int oc = oBase + nt * 16 + m;
            #pragma unroll
            for (int reg = 0; reg < 4; reg++) {
                int col = tX + quad * 4 + reg;
                float v = acc[mt][nt][reg];
                if (RELU) v = fmaxf(v, 0.f);
                out[((size_t)(b * HW + row) * HW + col) * OC + oc] = f2b(v);
            }
        }
    }
}

// ---------------------------------------------------------------- conv1x1 MFMA: (T2*smap) x w1s[b] + A residual
// block: 256 px x 128 oc; wave = 64 px x 128 oc (mt 0..3, nt 0..7)
__global__ __launch_bounds__(256, 2) void conv1x1_mfma(const bf16* __restrict__ t3,
                                                       const float* __restrict__ smap,
                                                       const bf16* __restrict__ w1s,
                                                       bf16* __restrict__ A) {
    __shared__ bf16 sX[256 * ICP];
    __shared__ bf16 sW1[128 * ICP];
    int p0 = blockIdx.x * 256;
    int oBase = blockIdx.y * 128;
    int b = blockIdx.z;
    int tid = threadIdx.x;
    int lane = tid & 63, wid = tid >> 6;
    int m = lane & 15, quad = lane >> 4;
    const bf16* wB = w1s + (size_t)b * 512 * 512;
    const bf16* tB = t3 + ((size_t)b << 14) * 512;
    const float* sm = smap + (b << 14);

    floatx4 acc[4][8];
    #pragma unroll
    for (int i = 0; i < 4; i++)
        #pragma unroll
        for (int j = 0; j < 8; j++)
            acc[i][j] = (floatx4){0.f, 0.f, 0.f, 0.f};

    for (int ic0 = 0; ic0 < 512; ic0 += 32) {
        __syncthreads();
        #pragma unroll
        for (int k = 0; k < 4; k++) {
            int e = tid + k * 256;            // 1024 = 256 px x 4 chunks
            int q = e & 3, p = e >> 2;
            float sc = sm[p0 + p];
            short8 v = *(const short8*)(tB + (size_t)(p0 + p) * 512 + ic0 + q * 8);
            short8 o;
            #pragma unroll
            for (int t = 0; t < 8; t++)
                o[t] = (short)fbits(s2f(v[t]) * sc);
            *(short8*)(sX + p * ICP + q * 8) = o;
        }
        #pragma unroll
        for (int k = 0; k < 2; k++) {
            int e = tid + k * 256;            // 512 = 128 oc x 4 chunks
            int q = e & 3, oc = e >> 2;
            *(short8*)(sW1 + oc * ICP + q * 8) =
                *(const short8*)(wB + (size_t)(oBase + oc) * 512 + ic0 + q * 8);
        }
        __syncthreads();
        short8 bfr[8];
        #pragma unroll
        for (int nt = 0; nt < 8; nt++)
            bfr[nt] = *(const short8*)(sW1 + (nt * 16 + m) * ICP + quad * 8);
        #pragma unroll
        for (int mt = 0; mt < 4; mt++) {
            short8 afr = *(const short8*)(sX + ((wid * 4 + mt) * 16 + m) * ICP + quad * 8);
            #pragma unroll
            for (int nt = 0; nt < 8; nt++)
                acc[mt][nt] = __builtin_amdgcn_mfma_f32_16x16x32_bf16(afr, bfr[nt], acc[mt][nt], 0, 0, 0);
        }
    }
    bf16* AB = A + ((size_t)b << 14) * 512;
    #pragma unroll
    for (int mt = 0; mt < 4; mt++) {
        #pragma unroll
        for (int nt = 0; nt < 8; nt++) {
            int oc = oBase + nt * 16 + m;
            #pragma unroll
            for (int reg = 0; reg < 4; reg++) {
                int p = p0 + wid * 64 + mt * 16 + quad * 4 + reg;
                size_t a = (size_t)p * 512 + oc;
                AB[a] = f2b(acc[mt][nt][reg] + b2f(AB[a]));
            }
        }
    }
}

// ---------------------------------------------------------------- sal: per-pixel channel max/mean
__global__ __launch_bounds__(256) void sal_pool(const bf16* __restrict__ t2, float* __restrict__ pool) {
    int pix = blockIdx.x * 4 + (threadIdx.x >> 6);
    int lane = threadIdx.x & 63;
    short8 v = *(const short8*)(t2 + (size_t)pix * 512 + lane * 8);
    float mx = -1e30f, sm = 0.f;
    #pragma unroll
    for (int i = 0; i < 8; i++) {
        float f = s2f(v[i]);
        mx = fmaxf(mx, f);
        sm += f;
    }
    #pragma unroll
    for (int off = 32; off > 0; off >>= 1) {
        mx = fmaxf(mx, __shfl_xor(mx, off));
        sm += __shfl_xor(sm, off);
    }
    if (lane == 0) {
        int b = pix >> 14, px = pix & (HWh - 1);
        pool[((size_t)(b * 2) << 14) + px] = mx;
        pool[((size_t)(b * 2 + 1) << 14) + px] = sm * (1.f / 512.f);
    }
}

// ---------------------------------------------------------------- sal: 5x5 conv + sigmoid
__global__ __launch_bounds__(256) void sal_conv(const float* __restrict__ pool,
                                                const float* __restrict__ wsal,
                                                float* __restrict__ smap) {
    int p = blockIdx.x * 256 + threadIdx.x;
    int b = p >> 14, px = p & (HWh - 1);
    int iy = px >> 7, ix = px & 127;
    float acc = 0.f;
    #pragma unroll
    for (int ch = 0; ch < 2; ch++)
        #pragma unroll
        for (int dy = 0; dy < 5; dy++)
            #pragma unroll
            for (int dx = 0; dx < 5; dx++) {
                int gy = iy + dy - 2, gx = ix + dx - 2;
                if (gy >= 0 && gy < Hh && gx >= 0 && gx < Wh)
                    acc += pool[((size_t)(b * 2 + ch) << 14) + gy * Wh + gx] *
                           wsal[ch * 25 + dy * 5 + dx];
            }
    smap[p] = 1.f / (1.f + expf(-acc));
}

// ---------------------------------------------------------------- chsum[b][c] = sum_px T2[px,c]*smap[px] (read-only)
__global__ __launch_bounds__(256) void sal_wsum(const bf16* __restrict__ t2,
                                                const float* __restrict__ smap,
                                                float* __restrict__ chsum) {
    int b = blockIdx.y;
    int p0 = blockIdx.x * 32;
    int t = threadIdx.x;                       // channels 2t, 2t+1
    float s0 = 0.f, s1 = 0.f;
    const bf16* tB = t2 + ((size_t)b << 14) * 512;
    #pragma unroll 4
    for (int k = 0; k < 32; k++) {
        int pix = p0 + k;
        float sc = smap[(b << 14) + pix];
        unsigned v = *(const unsigned*)(tB + (size_t)pix * 512 + 2 * t);
        s0 += s2f((short)(v & 0xffff)) * sc;
        s1 += s2f((short)(v >> 16)) * sc;
    }
    atomicAdd(&chsum[b * 512 + 2 * t], s0);
    atomicAdd(&chsum[b * 512 + 2 * t + 1], s1);
}

// ---------------------------------------------------------------- cal MLP -> sigmoid scale per (b,c)
__global__ __launch_bounds__(512) void cal_kernel(const float* __restrict__ chsum,
                                                  const float* __restrict__ wca1,
                                                  const float* __restrict__ wca2,
                                                  float* __restrict__ scale) {
    int b = blockIdx.x;
    __shared__ float sMean[512];
    __shared__ float sH[32];
    sMean[threadIdx.x] = chsum[b * C8 + threadIdx.x] * (1.f / 16384.f);
    __syncthreads();
    if (threadIdx.x < 32) {
        float a = 0.f;
        for (int cc = 0; cc < 512; cc++)
            a += wca1[threadIdx.x * 512 + cc] * sMean[cc];
        sH[threadIdx.x] = fmaxf(a, 0.f);
    }
    __syncthreads();
    float a = 0.f;
    #pragma unroll
    for (int j = 0; j < 32; j++)
        a += wca2[threadIdx.x * 32 + j] * sH[j];
    scale[b * C8 + threadIdx.x] = 1.f / (1.f + expf(-a));
}

// ---------------------------------------------------------------- ibwt: A NHWC -> E NHWC (B,256,256,64)
__global__ __launch_bounds__(256) void ibwt_nhwc(const bf16* __restrict__ A, bf16* __restrict__ E) {
    int idx = blockIdx.x * 256 + threadIdx.x;
    int c = idx & 63;
    int j = (idx >> 6) & 127;
    int i = (idx >> 13) & 127;
    int b = idx >> 20;
    size_t base = (size_t)(idx >> 6) * 512 + c;
    float xs[8];
    #pragma unroll
    for (int k = 0; k < 8; k++)
        xs[k] = b2f(A[base + k * 64]) * 0.5f;
    float a00 = xs[0] - xs[1] - xs[2] + xs[3] + xs[4] - xs[5] + xs[6] - xs[7];
    float a10 = xs[0] - xs[1] + xs[2] - xs[3] - xs[4] + xs[5] - xs[6] + xs[7];
    float a01 = xs[0] + xs[1] - xs[2] - xs[3] - xs[4] - xs[5] + xs[6] + xs[7];
    float a11 = xs[0] + xs[1] + xs[2] + xs[3] + xs[4] + xs[5] + xs[6] + xs[7];
    bf16* Ep = E + ((size_t)((b * H + 2 * i) * W + 2 * j)) * 64 + c;
    Ep[0]           = f2b(a00);
    Ep[64]          = f2b(a01);
    Ep[W * 64]      = f2b(a10);
    Ep[W * 64 + 64] = f2b(a11);
}

// ---------------------------------------------------------------- final: relu(conv3x3(E)) + w_final@x -> NCHW fp32
__global__ __launch_bounds__(256, 2) void final_mfma(const bf16* __restrict__ E,
                                                     const bf16* __restrict__ wr3,
                                                     const float* __restrict__ x,
                                                     const bf16* __restrict__ wfr,
                                                     float* __restrict__ out) {
    __shared__ bf16 sIn[18 * 18 * ICP];
    __shared__ bf16 sW9[9 * 64 * ICP];
    const int tilesX = W / 16;
    int tX = (blockIdx.x % tilesX) * 16;
    int tY = (blockIdx.x / tilesX) * 16;
    int b = blockIdx.z;
    int tid = threadIdx.x;
    int lane = tid & 63, wid = tid >> 6;
    int m = lane & 15, quad = lane >> 4;

    floatx4 acc[4][4];
    #pragma unroll
    for (int i = 0; i < 4; i++)
        #pragma unroll
        for (int j = 0; j < 4; j++)
            acc[i][j] = (floatx4){0.f, 0.f, 0.f, 0.f};

    const bf16* inB = E + (size_t)b * HWf * 64;
    for (int ic0 = 0; ic0 < 64; ic0 += 32) {
        __syncthreads();
        for (int e = tid; e < 18 * 18 * 4; e += 256) {
            int q = e & 3, cell = e >> 2;
            int r = cell / 18, c = cell - r * 18;
            int gr = tY + r - 1, gc = tX + c - 1;
            short8 v = {0, 0, 0, 0, 0, 0, 0, 0};
            if (gr >= 0 && gr < H && gc >= 0 && gc < W)
                v = *(const short8*)(inB + (size_t)(gr * W + gc) * 64 + ic0 + q * 8);
            *(short8*)(sIn + cell * ICP + q * 8) = v;
        }
        for (int e = tid; e < 2304; e += 256) {
            int q = e & 3, row = e >> 2;
            int tap = row >> 6, oc = row & 63;
            short8 v = *(const short8*)(wr3 + (size_t)(tap * 64 + oc) * 64 + ic0 + q * 8);
            *(short8*)(sW9 + row * ICP + q * 8) = v;
        }
        __syncthreads();
        #pragma unroll
        for (int dy = 0; dy < 3; dy++) {
            #pragma unroll
            for (int dx = 0; dx < 3; dx++) {
                short8 bfr[4];
                #pragma unroll
                for (int nt = 0; nt < 4; nt++)
                    bfr[nt] = *(const short8*)(sW9 + ((dy * 3 + dx) * 64 + nt * 16 + m) * ICP + quad * 8);
                #pragma unroll
                for (int mt = 0; mt < 4; mt++) {
                    int r = wid * 4 + mt;
                    short8 afr = *(const short8*)(sIn + ((r + dy) * 18 + m + dx) * ICP + quad * 8);
                    #pragma unroll
                    for (int nt = 0; nt < 4; nt++)
                        acc[mt][nt] = __builtin_amdgcn_mfma_f32_16x16x32_bf16(afr, bfr[nt], acc[mt][nt], 0, 0, 0);
                }
            }
        }
    }
    #pragma unroll
    for (int i = 0; i < 4; i++)
        #pragma unroll
        for (int j = 0; j < 4; j++)
            #pragma unroll
            for (int r = 0; r < 4; r++)
                acc[i][j][r] = fmaxf(acc[i][j][r], 0.f);

    // phase 2: + 1x1(x), x NCHW fp32 staged into halo-center (tap slot 1)
    for (int icc = 0; icc < 64; icc += 32) {
        __syncthreads();
        for (int e = tid; e < 2048; e += 256) {       // 32 ic x 16 r x 4 col-quads
            int c4 = e & 3, r = (e >> 2) & 15, ic = e >> 6;
            float4 v = *(const float4*)(x + ((size_t)(b * 64 + icc + ic) * H + tY + r) * W + tX + c4 * 4);
            bf16* dst = sIn + ((r + 1) * 18 + c4 * 4 + 1) * ICP + ic;
            dst[0]       = f2b(v.x);
            dst[ICP]     = f2b(v.y);
            dst[2 * ICP] = f2b(v.z);
            dst[3 * ICP] = f2b(v.w);
        }
        {
            int q = tid & 3, oc = tid >> 2;
            *(short8*)(sW9 + (64 + oc) * ICP + q * 8) =
                *(const short8*)(wfr + oc * 64 + icc + q * 8);
        }
        __syncthreads();
        short8 bfr[4];
        #pragma unroll
        for (int nt = 0; nt < 4; nt++)
            bfr[nt] = *(const short8*)(sW9 + (64 + nt * 16 + m) * ICP + quad * 8);
        #pragma unroll
        for (int mt = 0; mt < 4; mt++) {
            int r = wid * 4 + mt;
            short8 afr = *(const short8*)(sIn + ((r + 1) * 18 + m + 1) * ICP + quad * 8);
            #pragma unroll
            for (int nt = 0; nt < 4; nt++)
                acc[mt][nt] = __builtin_amdgcn_mfma_f32_16x16x32_bf16(afr, bfr[nt], acc[mt][nt], 0, 0, 0);
        }
    }
    #pragma unroll
    for (int mt = 0; mt < 4; mt++) {
        int gr = tY + wid * 4 + mt;
        #pragma unroll
        for (int nt = 0; nt < 4; nt++) {
            int oc = nt * 16 + m;
            *(floatx4*)(out + ((size_t)(b * 64 + oc) * H + gr) * W + tX + quad * 4) = acc[mt][nt];
        }
    }
}

// ---------------------------------------------------------------- launch
extern "C" void kernel_launch(void* const* d_in, const int* in_sizes, int n_in,
                              void* d_out, int out_size, void* d_ws, size_t ws_size,
                              hipStream_t stream) {
    const float* x       = (const float*)d_in[0];
    const float* w_body1 = (const float*)d_in[1];
    const float* w_body2 = (const float*)d_in[2];
    const float* w_sal   = (const float*)d_in[3];
    const float* w_ca1   = (const float*)d_in[4];
    const float* w_ca2   = (const float*)d_in[5];
    const float* w_1x1   = (const float*)d_in[6];
    const float* w_3x3   = (const float*)d_in[7];
    const float* w_final = (const float*)d_in[8];

    char* ws = (char*)d_ws;
    bf16*  A     = (bf16*)(ws + 0);            // 67,108,864  NHWC (B,128,128,512): x_bwt, later conv1x1 out
    bf16*  T2    = (bf16*)(ws + 67108864);     // 67,108,864  NHWC body2 out; later E aliases it
    bf16*  T1    = (bf16*)(ws + 134217728);    //  8,388,608  body1 out (dead after body2)
    float* pool  = (float*)(ws + 134217728);   //    524,288 (after body2, T1 dead)
    float* smap  = (float*)(ws + 134742016);   //    262,144
    float* chsum = (float*)(ws + 135004160);   //      8,192
    float* scale = (float*)(ws + 135012352);   //      8,192
    bf16*  w1s   = (bf16*)(ws + 135020544);    //  2,097,152
    bf16*  wr3   = (bf16*)(ws + 137117696);    //     73,728
    bf16*  wfr   = (bf16*)(ws + 137191424);    //      8,192
    bf16*  E     = T2;
    bf16*  wr1   = (bf16*)d_out;               //    589,824 (parked in dead d_out)
    bf16*  wr2   = (bf16*)((char*)d_out + 589824);

    prep_wr<64, 512><<<1152, 256, 0, stream>>>(w_body1, wr1);
    prep_wr<512, 64><<<1152, 256, 0, stream>>>(w_body2, wr2);
    bwt_nhwc<<<dim3(256, 1, 4), 256, 0, stream>>>(x, A);
    conv3x3_mfma<512, 64, 128, true, 1><<<dim3(64, 1, 4), 256, 0, stream>>>(A, wr1, T1);
    conv3x3_mfma<64, 512, 128, false, 2><<<dim3(64, 8, 4), 256, 0, stream>>>(T1, wr2, T2);
    sal_pool<<<16384, 256, 0, stream>>>(T2, pool);
    sal_conv<<<256, 256, 0, stream>>>(pool, w_sal, smap);
    hipMemsetAsync(chsum, 0, 4 * 512 * sizeof(float), stream);
    sal_wsum<<<dim3(512, 4), 256, 0, stream>>>(T2, smap, chsum);
    cal_kernel<<<4, 512, 0, stream>>>(chsum, w_ca1, w_ca2, scale);
    prep_w1s<<<4096, 256, 0, stream>>>(w_1x1, scale, w1s);
    prep_wr<64, 64><<<144, 256, 0, stream>>>(w_3x3, wr3);
    prep_wfr<<<16, 256, 0, stream>>>(w_final, wfr);
    conv1x1_mfma<<<dim3(64, 4, 4), 256, 0, stream>>>(T2, smap, w1s, A);
    ibwt_nhwc<<<16384, 256, 0, stream>>>(A, E);
    final_mfma<<<dim3(256, 1, 4), 256, 0, stream>>>(E, wr3, x, wfr, (float*)d_out);
}

// Round 5
// 445.220 us; speedup vs baseline: 21.3815x; 1.0752x over previous
//
#include <hip/hip_runtime.h>
#include <hip/hip_bf16.h>

typedef __hip_bfloat16 bf16;
using short8  = __attribute__((ext_vector_type(8))) short;
using floatx4 = __attribute__((ext_vector_type(4))) float;

__device__ __forceinline__ float b2f(bf16 v) { return __bfloat162float(v); }
__device__ __forceinline__ bf16 f2b(float v) { return __float2bfloat16(v); }
__device__ __forceinline__ float s2f(short s) {
    return __uint_as_float(((unsigned)(unsigned short)s) << 16);
}
__device__ __forceinline__ unsigned short fbits(float v) {
    bf16 b = f2b(v);
    return *(unsigned short*)&b;
}

constexpr int H = 256, W = 256, Hh = 128, Wh = 128, C8 = 512;
constexpr int HWh = Hh * Wh;   // 16384
constexpr int HWf = H * W;     // 65536
constexpr int ICP = 40;        // LDS ic stride (32+8 pad): lane stride 20 dwords -> 2-way (free)

// ---------------------------------------------------------------- weight swizzles
// conv3x3 weights -> [tap][kc][g][nt][lane][8]  (exact MFMA B-fragment order)
template<int OC, int IC>
__global__ __launch_bounds__(256) void prep_wrT(const float* __restrict__ w, bf16* __restrict__ wrT) {
    int idx = blockIdx.x * 256 + threadIdx.x;
    if (idx >= 9 * OC * IC) return;
    constexpr int G = OC / 64, KC = IC / 32;
    int j = idx & 7;
    int l = (idx >> 3) & 63;
    int nt = (idx >> 9) & 3;
    int rest = idx >> 11;
    int g = rest % G;
    int rest2 = rest / G;
    int kc = rest2 % KC;
    int tap = rest2 / KC;
    int oc = g * 64 + nt * 16 + (l & 15);
    int ic = kc * 32 + (l >> 4) * 8 + j;
    wrT[idx] = f2b(w[(oc * IC + ic) * 9 + tap]);
}

// w_1x1 * cal_scale -> [b][kc 16][g 4][nt 8][lane][8]
__global__ __launch_bounds__(256) void prep_w1sT(const float* __restrict__ w1,
                                                 const float* __restrict__ scale,
                                                 bf16* __restrict__ w1sT) {
    int idx = blockIdx.x * 256 + threadIdx.x;   // 4*512*512
    int j = idx & 7;
    int l = (idx >> 3) & 63;
    int nt = (idx >> 9) & 7;
    int g = (idx >> 12) & 3;
    int kc = (idx >> 14) & 15;
    int b = idx >> 18;
    int oc = g * 128 + nt * 16 + (l & 15);
    int ic = kc * 32 + (l >> 4) * 8 + j;
    w1sT[idx] = f2b(w1[oc * 512 + ic] * scale[b * 512 + ic]);
}

// w_final -> [kc 2][nt 4][lane][8]
__global__ __launch_bounds__(256) void prep_wfrT(const float* __restrict__ wf, bf16* __restrict__ wfrT) {
    int idx = blockIdx.x * 256 + threadIdx.x;   // 4096
    int j = idx & 7;
    int l = (idx >> 3) & 63;
    int nt = (idx >> 9) & 3;
    int kc = idx >> 11;
    int oc = nt * 16 + (l & 15);
    int ic = kc * 32 + (l >> 4) * 8 + j;
    wfrT[idx] = f2b(wf[oc * 64 + ic]);
}

// ---------------------------------------------------------------- bwt, LDS-transposed
constexpr int XROW = 130;
__global__ __launch_bounds__(256, 2) void bwt_nhwc(const float* __restrict__ x, bf16* __restrict__ A) {
    __shared__ unsigned short sX[2 * 64 * XROW];
    int bx = blockIdx.x;
    int i = bx >> 1, j0 = (bx & 1) * 64;
    int b = blockIdx.z;
    int tid = threadIdx.x;
    for (int k = 0; k < 16; k++) {
        int e = tid + k * 256;
        int w4 = e & 31, r = (e >> 5) & 1, c = e >> 6;
        float4 v = *(const float4*)(x + (((size_t)(b * 64 + c) * H + 2 * i + r) * W) + j0 * 2 + w4 * 4);
        unsigned lo = ((unsigned)fbits(v.y) << 16) | fbits(v.x);
        unsigned hi = ((unsigned)fbits(v.w) << 16) | fbits(v.z);
        unsigned short* dst = sX + (r * 64 + c) * XROW + w4 * 4;
        *(unsigned*)(dst) = lo;
        *(unsigned*)(dst + 2) = hi;
    }
    __syncthreads();
    int c = tid & 63, wid = tid >> 6;
    for (int k = 0; k < 16; k++) {
        int jr = wid * 16 + k;
        unsigned ev = *(const unsigned*)(sX + c * XROW + jr * 2);
        unsigned od = *(const unsigned*)(sX + (64 + c) * XROW + jr * 2);
        float x1 = s2f((short)(ev & 0xffff)) * 0.5f;
        float x3 = s2f((short)(ev >> 16)) * 0.5f;
        float x2 = s2f((short)(od & 0xffff)) * 0.5f;
        float x4 = s2f((short)(od >> 16)) * 0.5f;
        float v[8];
        v[0] =  x1 + x2 + x3 + x4;
        v[1] = -x1 - x2 + x3 + x4;
        v[2] = -x1 + x2 - x3 + x4;
        v[3] =  x1 - x2 - x3 + x4;
        v[4] =  x1 + x2 - x3 - x4;
        v[5] = -x1 + x2 + x3 - x4;
        v[6] =  x1 - x2 + x3 - x4;
        v[7] = -x1 - x2 - x3 - x4;
        size_t base = ((size_t)((b * Hh + i) * Wh) + j0 + jr) * 512 + c;
        #pragma unroll
        for (int band = 0; band < 8; band++)
            A[base + band * 64] = f2b(v[band]);
    }
}

// ---------------------------------------------------------------- conv3x3 MFMA, dbuf LDS + direct-global weights
template<int IC, int OC, int HW, int TR, bool RELU>
__global__ __launch_bounds__(256, 2) void conv3x3_mfma(const bf16* __restrict__ in,
                                                       const bf16* __restrict__ wrT,
                                                       bf16* __restrict__ out) {
    constexpr int MT = TR / 4, NKC = IC / 32, G = OC / 64;
    constexpr int CELLS = (TR + 2) * 18;
    constexpr int NLD = (CELLS * 4 + 255) / 256;
    __shared__ bf16 sIn[2][CELLS * ICP];

    const int tilesX = HW / 16;
    int tX = (blockIdx.x % tilesX) * 16;
    int tY = (blockIdx.x / tilesX) * TR;
    int g = blockIdx.y;
    int b = blockIdx.z;
    int tid = threadIdx.x;
    int lane = tid & 63, wid = tid >> 6;
    int m = lane & 15, quad = lane >> 4;

    floatx4 acc[MT][4];
    #pragma unroll
    for (int i = 0; i < MT; i++)
        #pragma unroll
        for (int j = 0; j < 4; j++)
            acc[i][j] = (floatx4){0.f, 0.f, 0.f, 0.f};

    const bf16* inB = in + (size_t)b * HW * HW * IC;

    auto load_tile = [&](int kc, short8* tmp) {
        #pragma unroll
        for (int k = 0; k < NLD; k++) {
            int e = tid + k * 256;
            tmp[k] = (short8){0, 0, 0, 0, 0, 0, 0, 0};
            if (e < CELLS * 4) {
                int q = e & 3, cell = e >> 2;
                int r = cell / 18, c = cell - r * 18;
                int gr = tY + r - 1, gc = tX + c - 1;
                if (gr >= 0 && gr < HW && gc >= 0 && gc < HW)
                    tmp[k] = *(const short8*)(inB + (size_t)(gr * HW + gc) * IC + kc * 32 + q * 8);
            }
        }
    };
    auto write_tile = [&](int buf, short8* tmp) {
        #pragma unroll
        for (int k = 0; k < NLD; k++) {
            int e = tid + k * 256;
            if (e < CELLS * 4) {
                int q = e & 3, cell = e >> 2;
                *(short8*)(sIn[buf] + cell * ICP + q * 8) = tmp[k];
            }
        }
    };

    {
        short8 t0[NLD];
        load_tile(0, t0);
        write_tile(0, t0);
    }
    for (int kc = 0; kc < NKC; kc++) {
        short8 nxt[NLD];
        __syncthreads();
        bool pf = (kc + 1 < NKC);
        if (pf) load_tile(kc + 1, nxt);        // issue loads; data consumed after compute
        const bf16* sbuf = sIn[kc & 1];
        #pragma unroll
        for (int dx = 0; dx < 3; dx++) {
            short8 arow[MT + 2];
            #pragma unroll
            for (int i = 0; i < MT + 2; i++)
                arow[i] = *(const short8*)(sbuf + ((wid * MT + i) * 18 + m + dx) * ICP + quad * 8);
            #pragma unroll
            for (int dy = 0; dy < 3; dy++) {
                int tap = dy * 3 + dx;
                const bf16* wt = wrT + ((size_t)((tap * NKC + kc) * G + g) * 4) * 512;
                short8 bfr[4];
                #pragma unroll
                for (int nt = 0; nt < 4; nt++)
                    bfr[nt] = *(const short8*)(wt + nt * 512 + lane * 8);
                #pragma unroll
                for (int mt = 0; mt < MT; mt++)
                    #pragma unroll
                    for (int nt = 0; nt < 4; nt++)
                        acc[mt][nt] = __builtin_amdgcn_mfma_f32_16x16x32_bf16(arow[mt + dy], bfr[nt], acc[mt][nt], 0, 0, 0);
            }
        }
        if (pf) write_tile((kc + 1) & 1, nxt);
    }
    #pragma unroll
    for (int mt = 0; mt < MT; mt++) {
        int row = tY + wid * MT + mt;
        #pragma unroll
        for (int nt = 0; nt < 4; nt++) {
            int oc = g * 64 + nt * 16 + m;
            #pragma unroll
            for (int reg = 0; reg < 4; reg++) {
                int col = tX + quad * 4 + reg;
                float v = acc[mt][nt][reg];
                if (RELU) v = fmaxf(v, 0.f);
                out[((size_t)(b * HW + row) * HW + col) * OC + oc] = f2b(v);
            }
        }
    }
}

// ---------------------------------------------------------------- conv1x1 MFMA: T2 x w1sT + smap in epilogue + A residual
__global__ __launch_bounds__(256, 2) void conv1x1_mfma(const bf16* __restrict__ t3,
                                                       const float* __restrict__ smap,
                                                       const bf16* __restrict__ w1sT,
                                                       bf16* __restrict__ A) {
    __shared__ bf16 sX[2][256 * ICP];
    int p0 = blockIdx.x * 256;
    int gB = blockIdx.y;
    int b = blockIdx.z;
    int tid = threadIdx.x;
    int lane = tid & 63, wid = tid >> 6;
    int m = lane & 15, quad = lane >> 4;
    const bf16* tB = t3 + ((size_t)b << 14) * 512;
    const float* sm = smap + (b << 14);

    floatx4 acc[4][8];
    #pragma unroll
    for (int i = 0; i < 4; i++)
        #pragma unroll
        for (int j = 0; j < 8; j++)
            acc[i][j] = (floatx4){0.f, 0.f, 0.f, 0.f};

    auto load_x = [&](int kc, short8* tmp) {
        #pragma unroll
        for (int k = 0; k < 4; k++) {
            int e = tid + k * 256;
            int q = e & 3, p = e >> 2;
            tmp[k] = *(const short8*)(tB + (size_t)(p0 + p) * 512 + kc * 32 + q * 8);
        }
    };
    auto write_x = [&](int buf, short8* tmp) {
        #pragma unroll
        for (int k = 0; k < 4; k++) {
            int e = tid + k * 256;
            int q = e & 3, p = e >> 2;
            *(short8*)(sX[buf] + p * ICP + q * 8) = tmp[k];
        }
    };

    {
        short8 t0[4];
        load_x(0, t0);
        write_x(0, t0);
    }
    for (int kc = 0; kc < 16; kc++) {
        short8 nxt[4];
        __syncthreads();
        bool pf = (kc + 1 < 16);
        if (pf) load_x(kc + 1, nxt);
        const bf16* sbuf = sX[kc & 1];
        const bf16* wt = w1sT + ((size_t)((b * 16 + kc) * 4 + gB) * 8) * 512;
        short8 bfr[8];
        #pragma unroll
        for (int nt = 0; nt < 8; nt++)
            bfr[nt] = *(const short8*)(wt + nt * 512 + lane * 8);
        #pragma unroll
        for (int mt = 0; mt < 4; mt++) {
            short8 afr = *(const short8*)(sbuf + ((wid * 4 + mt) * 16 + m) * ICP + quad * 8);
            #pragma unroll
            for (int nt = 0; nt < 8; nt++)
                acc[mt][nt] = __builtin_amdgcn_mfma_f32_16x16x32_bf16(afr, bfr[nt], acc[mt][nt], 0, 0, 0);
        }
        if (pf) write_x((kc + 1) & 1, nxt);
    }
    bf16* AB = A + ((size_t)b << 14) * 512;
    #pragma unroll
    for (int mt = 0; mt < 4; mt++) {
        float smv[4];
        *(float4*)smv = *(const float4*)(sm + p0 + wid * 64 + mt * 16 + quad * 4);
        #pragma unroll
        for (int nt = 0; nt < 8; nt++) {
            int oc = gB * 128 + nt * 16 + m;
            #pragma unroll
            for (int reg = 0; reg < 4; reg++) {
                int p = p0 + wid * 64 + mt * 16 + quad * 4 + reg;
                size_t a = (size_t)p * 512 + oc;
                AB[a] = f2b(acc[mt][nt][reg] * smv[reg] + b2f(AB[a]));
            }
        }
    }
}

// ---------------------------------------------------------------- sal: per-pixel channel max/mean
__global__ __launch_bounds__(256) void sal_pool(const bf16* __restrict__ t2, float* __restrict__ pool) {
    int pix = blockIdx.x * 4 + (threadIdx.x >> 6);
    int lane = threadIdx.x & 63;
    short8 v = *(const short8*)(t2 + (size_t)pix * 512 + lane * 8);
    float mx = -1e30f, sm = 0.f;
    #pragma unroll
    for (int i = 0; i < 8; i++) {
        float f = s2f(v[i]);
        mx = fmaxf(mx, f);
        sm += f;
    }
    #pragma unroll
    for (int off = 32; off > 0; off >>= 1) {
        mx = fmaxf(mx, __shfl_xor(mx, off));
        sm += __shfl_xor(sm, off);
    }
    if (lane == 0) {
        int b = pix >> 14, px = pix & (HWh - 1);
        pool[((size_t)(b * 2) << 14) + px] = mx;
        pool[((size_t)(b * 2 + 1) << 14) + px] = sm * (1.f / 512.f);
    }
}

// ---------------------------------------------------------------- sal: 5x5 conv + sigmoid
__global__ __launch_bounds__(256) void sal_conv(const float* __restrict__ pool,
                                                const float* __restrict__ wsal,
                                                float* __restrict__ smap) {
    int p = blockIdx.x * 256 + threadIdx.x;
    int b = p >> 14, px = p & (HWh - 1);
    int iy = px >> 7, ix = px & 127;
    float acc = 0.f;
    #pragma unroll
    for (int ch = 0; ch < 2; ch++)
        #pragma unroll
        for (int dy = 0; dy < 5; dy++)
            #pragma unroll
            for (int dx = 0; dx < 5; dx++) {
                int gy = iy + dy - 2, gx = ix + dx - 2;
                if (gy >= 0 && gy < Hh && gx >= 0 && gx < Wh)
                    acc += pool[((size_t)(b * 2 + ch) << 14) + gy * Wh + gx] *
                           wsal[ch * 25 + dy * 5 + dx];
            }
    smap[p] = 1.f / (1.f + expf(-acc));
}

// ---------------------------------------------------------------- chsum[b][c] = sum_px T2[px,c]*smap[px]
__global__ __launch_bounds__(256) void sal_wsum(const bf16* __restrict__ t2,
                                                const float* __restrict__ smap,
                                                float* __restrict__ chsum) {
    int b = blockIdx.y;
    int p0 = blockIdx.x * 32;
    int t = threadIdx.x;
    float s0 = 0.f, s1 = 0.f;
    const bf16* tB = t2 + ((size_t)b << 14) * 512;
    #pragma unroll 4
    for (int k = 0; k < 32; k++) {
        int pix = p0 + k;
        float sc = smap[(b << 14) + pix];
        unsigned v = *(const unsigned*)(tB + (size_t)pix * 512 + 2 * t);
        s0 += s2f((short)(v & 0xffff)) * sc;
        s1 += s2f((short)(v >> 16)) * sc;
    }
    atomicAdd(&chsum[b * 512 + 2 * t], s0);
    atomicAdd(&chsum[b * 512 + 2 * t + 1], s1);
}

// ---------------------------------------------------------------- cal MLP -> sigmoid scale per (b,c)
__global__ __launch_bounds__(512) void cal_kernel(const float* __restrict__ chsum,
                                                  const float* __restrict__ wca1,
                                                  const float* __restrict__ wca2,
                                                  float* __restrict__ scale) {
    int b = blockIdx.x;
    __shared__ float sMean[512];
    __shared__ float sH[32];
    sMean[threadIdx.x] = chsum[b * C8 + threadIdx.x] * (1.f / 16384.f);
    __syncthreads();
    if (threadIdx.x < 32) {
        float a = 0.f;
        for (int cc = 0; cc < 512; cc++)
            a += wca1[threadIdx.x * 512 + cc] * sMean[cc];
        sH[threadIdx.x] = fmaxf(a, 0.f);
    }
    __syncthreads();
    float a = 0.f;
    #pragma unroll
    for (int j = 0; j < 32; j++)
        a += wca2[threadIdx.x * 32 + j] * sH[j];
    scale[b * C8 + threadIdx.x] = 1.f / (1.f + expf(-a));
}

// ---------------------------------------------------------------- ibwt: A NHWC -> E NHWC
__global__ __launch_bounds__(256) void ibwt_nhwc(const bf16* __restrict__ A, bf16* __restrict__ E) {
    int idx = blockIdx.x * 256 + threadIdx.x;
    int c = idx & 63;
    int j = (idx >> 6) & 127;
    int i = (idx >> 13) & 127;
    int b = idx >> 20;
    size_t base = (size_t)(idx >> 6) * 512 + c;
    float xs[8];
    #pragma unroll
    for (int k = 0; k < 8; k++)
        xs[k] = b2f(A[base + k * 64]) * 0.5f;
    float a00 = xs[0] - xs[1] - xs[2] + xs[3] + xs[4] - xs[5] + xs[6] - xs[7];
    float a10 = xs[0] - xs[1] + xs[2] - xs[3] - xs[4] + xs[5] - xs[6] + xs[7];
    float a01 = xs[0] + xs[1] - xs[2] - xs[3] - xs[4] - xs[5] + xs[6] + xs[7];
    float a11 = xs[0] + xs[1] + xs[2] + xs[3] + xs[4] + xs[5] + xs[6] + xs[7];
    bf16* Ep = E + ((size_t)((b * H + 2 * i) * W + 2 * j)) * 64 + c;
    Ep[0]           = f2b(a00);
    Ep[64]          = f2b(a01);
    Ep[W * 64]      = f2b(a10);
    Ep[W * 64 + 64] = f2b(a11);
}

// ---------------------------------------------------------------- final: relu(conv3x3(E)) + w_final@x -> NCHW fp32
__global__ __launch_bounds__(256, 2) void final_mfma(const bf16* __restrict__ E,
                                                     const bf16* __restrict__ wr3T,
                                                     const float* __restrict__ x,
                                                     const bf16* __restrict__ wfrT,
                                                     float* __restrict__ out) {
    constexpr int CELLS = 18 * 18;
    __shared__ bf16 sIn[2][CELLS * ICP];
    const int tilesX = W / 16;
    int tX = (blockIdx.x % tilesX) * 16;
    int tY = (blockIdx.x / tilesX) * 16;
    int b = blockIdx.z;
    int tid = threadIdx.x;
    int lane = tid & 63, wid = tid >> 6;
    int m = lane & 15, quad = lane >> 4;

    floatx4 acc[4][4];
    #pragma unroll
    for (int i = 0; i < 4; i++)
        #pragma unroll
        for (int j = 0; j < 4; j++)
            acc[i][j] = (floatx4){0.f, 0.f, 0.f, 0.f};

    const bf16* inB = E + (size_t)b * HWf * 64;

    auto load_e = [&](int kc, short8* tmp) {
        #pragma unroll
        for (int k = 0; k < 6; k++) {
            int e = tid + k * 256;
            tmp[k] = (short8){0, 0, 0, 0, 0, 0, 0, 0};
            if (e < CELLS * 4) {
                int q = e & 3, cell = e >> 2;
                int r = cell / 18, c = cell - r * 18;
                int gr = tY + r - 1, gc = tX + c - 1;
                if (gr >= 0 && gr < H && gc >= 0 && gc < W)
                    tmp[k] = *(const short8*)(inB + (size_t)(gr * W + gc) * 64 + kc * 32 + q * 8);
            }
        }
    };
    auto write_e = [&](int buf, short8* tmp) {
        #pragma unroll
        for (int k = 0; k < 6; k++) {
            int e = tid + k * 256;
            if (e < CELLS * 4) {
                int q = e & 3, cell = e >> 2;
                *(short8*)(sIn[buf] + cell * ICP + q * 8) = tmp[k];
            }
        }
    };
    auto compute_e = [&](int kc, int buf) {
        const bf16* sbuf = sIn[buf];
        #pragma unroll
        for (int dx = 0; dx < 3; dx++) {
            short8 arow[6];
            #pragma unroll
            for (int i = 0; i < 6; i++)
                arow[i] = *(const short8*)(sbuf + ((wid * 4 + i) * 18 + m + dx) * ICP + quad * 8);
            #pragma unroll
            for (int dy = 0; dy < 3; dy++) {
                int tap = dy * 3 + dx;
                const bf16* wt = wr3T + ((size_t)(tap * 2 + kc) * 4) * 512;
                short8 bfr[4];
                #pragma unroll
                for (int nt = 0; nt < 4; nt++)
                    bfr[nt] = *(const short8*)(wt + nt * 512 + lane * 8);
                #pragma unroll
                for (int mt = 0; mt < 4; mt++)
                    #pragma unroll
                    for (int nt = 0; nt < 4; nt++)
                        acc[mt][nt] = __builtin_amdgcn_mfma_f32_16x16x32_bf16(arow[mt + dy], bfr[nt], acc[mt][nt], 0, 0, 0);
            }
        }
    };
    auto load_xx = [&](int kc, float4* xt) {
        #pragma unroll
        for (int k = 0; k < 8; k++) {
            int e = tid + k * 256;
            int c4 = e & 3, r = (e >> 2) & 15, ic = e >> 6;
            xt[k] = *(const float4*)(x + ((size_t)(b * 64 + kc * 32 + ic) * H + tY + r) * W + tX + c4 * 4);
        }
    };
    auto write_xx = [&](int buf, float4* xt) {
        #pragma unroll
        for (int k = 0; k < 8; k++) {
            int e = tid + k * 256;
            int c4 = e & 3, r = (e >> 2) & 15, ic = e >> 6;
            bf16* dst = sIn[buf] + ((r + 1) * 18 + c4 * 4 + 1) * ICP + ic;
            dst[0]       = f2b(xt[k].x);
            dst[ICP]     = f2b(xt[k].y);
            dst[2 * ICP] = f2b(xt[k].z);
            dst[3 * ICP] = f2b(xt[k].w);
        }
    };
    auto compute_x = [&](int kc, int buf) {
        const bf16* wt = wfrT + (size_t)(kc * 4) * 512;
        short8 bfr[4];
        #pragma unroll
        for (int nt = 0; nt < 4; nt++)
            bfr[nt] = *(const short8*)(wt + nt * 512 + lane * 8);
        #pragma unroll
        for (int mt = 0; mt < 4; mt++) {
            short8 afr = *(const short8*)(sIn[buf] + ((wid * 4 + mt + 1) * 18 + m + 1) * ICP + quad * 8);
            #pragma unroll
            for (int nt = 0; nt < 4; nt++)
                acc[mt][nt] = __builtin_amdgcn_mfma_f32_16x16x32_bf16(afr, bfr[nt], acc[mt][nt], 0, 0, 0);
        }
    };

    {
        short8 t0[6];
        load_e(0, t0);
        write_e(0, t0);
        load_e(1, t0);
        write_e(1, t0);
    }
    __syncthreads();
    compute_e(0, 0);
    __syncthreads();
    {
        float4 xt[8];
        load_xx(0, xt);
        compute_e(1, 1);
        #pragma unroll
        for (int i = 0; i < 4; i++)
            #pragma unroll
            for (int j = 0; j < 4; j++)
                #pragma unroll
                for (int r = 0; r < 4; r++)
                    acc[i][j][r] = fmaxf(acc[i][j][r], 0.f);
        write_xx(0, xt);
    }
    __syncthreads();
    {
        float4 xt[8];
        load_xx(1, xt);
        compute_x(0, 0);
        write_xx(1, xt);
    }
    __syncthreads();
    compute_x(1, 1);

    #pragma unroll
    for (int mt = 0; mt < 4; mt++) {
        int gr = tY + wid * 4 + mt;
        #pragma unroll
        for (int nt = 0; nt < 4; nt++) {
            int oc = nt * 16 + m;
            *(floatx4*)(out + ((size_t)(b * 64 + oc) * H + gr) * W + tX + quad * 4) = acc[mt][nt];
        }
    }
}

// ---------------------------------------------------------------- launch
extern "C" void kernel_launch(void* const* d_in, const int* in_sizes, int n_in,
                              void* d_out, int out_size, void* d_ws, size_t ws_size,
                              hipStream_t stream) {
    const float* x       = (const float*)d_in[0];
    const float* w_body1 = (const float*)d_in[1];
    const float* w_body2 = (const float*)d_in[2];
    const float* w_sal   = (const float*)d_in[3];
    const float* w_ca1   = (const float*)d_in[4];
    const float* w_ca2   = (const float*)d_in[5];
    const float* w_1x1   = (const float*)d_in[6];
    const float* w_3x3   = (const float*)d_in[7];
    const float* w_final = (const float*)d_in[8];

    char* ws = (char*)d_ws;
    bf16*  A     = (bf16*)(ws + 0);            // 67,108,864  NHWC (B,128,128,512)
    bf16*  T2    = (bf16*)(ws + 67108864);     // 67,108,864  NHWC body2 out; E aliases later
    bf16*  T1    = (bf16*)(ws + 134217728);    //  8,388,608  body1 out (dead after body2)
    float* pool  = (float*)(ws + 134217728);   //    524,288 (T1 dead by then)
    float* smap  = (float*)(ws + 134742016);   //    262,144
    float* chsum = (float*)(ws + 135004160);   //      8,192
    float* scale = (float*)(ws + 135012352);   //      8,192
    bf16*  w1sT  = (bf16*)(ws + 135020544);    //  2,097,152
    bf16*  wr3T  = (bf16*)(ws + 137117696);    //     73,728
    bf16*  wfrT  = (bf16*)(ws + 137191424);    //      8,192
    bf16*  E     = T2;
    bf16*  wr1T  = (bf16*)d_out;               //    589,824 (parked in dead d_out)
    bf16*  wr2T  = (bf16*)((char*)d_out + 589824);

    prep_wrT<64, 512><<<1152, 256, 0, stream>>>(w_body1, wr1T);
    prep_wrT<512, 64><<<1152, 256, 0, stream>>>(w_body2, wr2T);
    bwt_nhwc<<<dim3(256, 1, 4), 256, 0, stream>>>(x, A);
    conv3x3_mfma<512, 64, 128, 8, true ><<<dim3(128, 1, 4), 256, 0, stream>>>(A, wr1T, T1);
    conv3x3_mfma<64, 512, 128, 16, false><<<dim3(64, 8, 4), 256, 0, stream>>>(T1, wr2T, T2);
    sal_pool<<<16384, 256, 0, stream>>>(T2, pool);
    sal_conv<<<256, 256, 0, stream>>>(pool, w_sal, smap);
    hipMemsetAsync(chsum, 0, 4 * 512 * sizeof(float), stream);
    sal_wsum<<<dim3(512, 4), 256, 0, stream>>>(T2, smap, chsum);
    cal_kernel<<<4, 512, 0, stream>>>(chsum, w_ca1, w_ca2, scale);
    prep_w1sT<<<4096, 256, 0, stream>>>(w_1x1, scale, w1sT);
    prep_wrT<64, 64><<<144, 256, 0, stream>>>(w_3x3, wr3T);
    prep_wfrT<<<16, 256, 0, stream>>>(w_final, wfrT);
    conv1x1_mfma<<<dim3(64, 4, 4), 256, 0, stream>>>(T2, smap, w1sT, A);
    ibwt_nhwc<<<16384, 256, 0, stream>>>(A, E);
    final_mfma<<<dim3(256, 1, 4), 256, 0, stream>>>(E, wr3T, x, wfrT, (float*)d_out);
}